// Round 2
// baseline (111.269 us; speedup 1.0000x reference)
//
#include <hip/hip_runtime.h>
#include <math.h>

// Problem constants (reference: N=16384, D=128, T=0.07)
#define NROWS 16384
#define DDIM  128
constexpr float TEMP = 0.07f;
// Pre-scale trick: x *= sqrt(log2(e)/T) so MFMA emits acc = S*<xi,xj> and
// row_lse = ln(sum exp2(acc)). The DIAGONAL (sim_ii = 1 exactly, rows unit
// norm) is masked out of the MFMA path and added analytically in finalize:
// rowsum_i = offdiag_fp8_sum_i + 2^S. Off-diag is only ~2.3% of rowsum, so
// fp8 e4m3 error there is damped ~44x -> absmax ~0.006 vs threshold 0.286.
constexpr float S_EXP = 1.44269504088896f / TEMP;  // 20.6099291

typedef __attribute__((ext_vector_type(4))) float f32x4;

// async 16B global -> LDS (lds dest = wave-uniform base + lane*16)
__device__ __forceinline__ void gload_lds16(const unsigned char* g, unsigned char* l) {
  __builtin_amdgcn_global_load_lds(
      (const __attribute__((address_space(1))) unsigned int*)g,
      (__attribute__((address_space(3))) unsigned int*)l, 16, 0, 0);
}

// Convert + pre-scale to fp8 e4m3 (OCP, RNE via v_cvt_pk_fp8_f32); zero accum/cnt.
__global__ void convert_k(const float* __restrict__ x, unsigned char* __restrict__ xb,
                          float* __restrict__ accum, int* __restrict__ cnt) {
  const float R = 4.53981419f;  // sqrt(S_EXP); |x*R| <= ~1.3, well inside e4m3 range
  int i = (blockIdx.x * blockDim.x + threadIdx.x) * 4;
  float4 v = *(const float4*)(x + i);
  int p = __builtin_amdgcn_cvt_pk_fp8_f32(v.x * R, v.y * R, 0, false);
  p = __builtin_amdgcn_cvt_pk_fp8_f32(v.z * R, v.w * R, p, true);
  *(int*)(xb + i) = p;
  if (blockIdx.x == 0 && threadIdx.x == 0) { *accum = 0.f; *cnt = 0; }
}

// Triangular Gram in fp8, SINGLE barrier per tile (round-0 structure had 2:
// barrier A existed only to protect the single-buffered csbuf; csbuf is now
// DOUBLE-buffered, so A is gone). Block (I,s): A-panel register-resident
// (16 VGPRs); d-tiles s==0: d=0..8 else 8s+1..8s+8. Tile (I,d), J=(I+d)%128;
// row-sums accumulate in regs; col-sums (mirror rows, d not in {0,64}) via
// csbuf[ti&1] -> deferred plain stores to colpart[d-1] (block-private, no
// cross-block RMW). Barrier-B-only correctness: every wave at B(ti) has
// finished compute(ti-1) [reads of panel[(ti+1)&1]] and csbuf[(ti-1)&1] is
// fully written; B's vmcnt(0) drain covers stage(ti) issued last iteration.
// LDS swizzle (1 B/elem): 16B chunk (col, kc16) at physical chunk
// col*8 + (kc16 ^ ((col>>1)&7)) -> staging coalesced (8 full 128B rows
// per call) AND consumer ds_read_b64 ~4-way bank spread (cheap).
// Read-side algebra hoist: swz=(colb>>1)&7 reduces to the LANE CONSTANT
// l15>>1, so all 16 B-frag addresses per tile are laneB + ct*2048 (imm)
// + ktofs[kt] (lane const) -> ~4 VALU/tile instead of ~80 (bit-identical
// addresses to round 0: value ((kt<<1)|(q>>1))^swz splits into disjoint
// bit fields (kt<<1)^(swz&6) and (q>>1)^(swz&1)).
// d==0 tile: diagonal element zeroed in epilogue (uniform-false elsewhere).
// 512 thr = 8 waves; wave w: rows h*32 (h=w>>1), cols chalf*64 (chalf=w&1).
// R8 lesson: launch_bounds min-waves stays 4 (8 forces spill).
__global__ __launch_bounds__(512, 4)
void gram_tri_k(const unsigned char* __restrict__ xb, float* __restrict__ rowpart,
                float* __restrict__ colpart) {
  __shared__ unsigned char panel[2][128 * DDIM];  // 2 x 16 KB
  __shared__ float csbuf[2][512];                 // 2 x 2 KB (double-buffered)

  const int tid = threadIdx.x;
  const int w = tid >> 6, lane = tid & 63;
  const int l15 = lane & 15, q = lane >> 4;
  const int I = (int)(blockIdx.x >> 3), s = (int)(blockIdx.x & 7);
  const int rI = I * 128;
  const int h = w >> 1, chalf = w & 1;
  const int dstart = (s == 0) ? 0 : 8 * s + 1;
  const int ntiles = (s == 0) ? 9 : 8;

  // A frags: 16x16x32 fp8 A[m=l15][k = q*8 + j] -> 8 contiguous bytes/lane
  long af[2][4];
  const unsigned char* gA = xb + (size_t)(rI + h * 32 + l15) * DDIM + q * 8;
#pragma unroll
  for (int rt = 0; rt < 2; ++rt)
#pragma unroll
    for (int kt = 0; kt < 4; ++kt)
      af[rt][kt] = *(const long*)(gA + rt * 16 * DDIM + kt * 32);

  // staging lane constants: call rr stages physical chunk (w*2+rr)*64+lane:
  // col = (w*2+rr)*8 + (lane>>3), kc16 = (lane&7) ^ ((col>>1)&7)
  const int sc8 = lane >> 3, sk8 = lane & 7;

  // B-frag LDS read lane constants (tile-invariant):
  // addr = laneB + ct*2048 + ktofs[kt]; all kt indices compile-time (rule #20)
  const int swz = l15 >> 1;  // == (colb>>1)&7 for every ct
  const int laneB = chalf * 8192 + l15 * 128 +
                    (((q >> 1) ^ (swz & 1)) << 4) + ((q & 1) << 3);
  int ktofs[4];
#pragma unroll
  for (int kt = 0; kt < 4; ++kt) ktofs[kt] = (((kt << 1) ^ (swz & 6)) << 4);

  // stage tile 0 into panel[0]
  {
    const unsigned char* gJ = xb + (size_t)(((I + dstart) & 127) * 128) * DDIM;
#pragma unroll
    for (int rr = 0; rr < 2; ++rr) {
      const int col = (w * 2 + rr) * 8 + sc8;
      gload_lds16(gJ + (size_t)col * DDIM + (sk8 ^ ((col >> 1) & 7)) * 16,
                  &panel[0][(w * 2 + rr) * 1024]);
    }
  }

  float rs[2][4];
#pragma unroll
  for (int rt = 0; rt < 2; ++rt)
#pragma unroll
    for (int r = 0; r < 4; ++r) rs[rt][r] = 0.f;

  for (int ti = 0; ti < ntiles; ++ti) {
    const int d = dstart + ti;
    __syncthreads();  // B: panel[ti&1] staged; csbuf[(ti-1)&1] complete;
                      //    panel[(ti+1)&1] and csbuf[ti&1] readers done
    // deferred colpart store for tile ti-1 (block-private plain store)
    if (ti > 0) {
      const int pd = d - 1;
      if (pd != 0 && pd != 64 && tid < 128) {
        const float* cb = csbuf[(ti - 1) & 1];
        colpart[(size_t)(pd - 1) * NROWS + ((I + pd) & 127) * 128 + tid] =
            cb[tid] + cb[128 + tid] + cb[256 + tid] + cb[384 + tid];
      }
    }
    // stage ti+1 into the OTHER buffer; full tile of compute to land
    if (ti + 1 < ntiles) {
      const unsigned char* gJ = xb + (size_t)(((I + d + 1) & 127) * 128) * DDIM;
      unsigned char* bn = panel[(ti + 1) & 1];
#pragma unroll
      for (int rr = 0; rr < 2; ++rr) {
        const int col = (w * 2 + rr) * 8 + sc8;
        gload_lds16(gJ + (size_t)col * DDIM + (sk8 ^ ((col >> 1) & 7)) * 16,
                    bn + (w * 2 + rr) * 1024);
      }
    }
    const unsigned char* Lb = panel[ti & 1] + laneB;
    const bool dz = (d == 0);  // uniform; only s==0/ti==0 blocks pay the mask

    float cstile[4];
#pragma unroll
    for (int ct = 0; ct < 4; ++ct) {
      long bfr[4];
#pragma unroll
      for (int kt = 0; kt < 4; ++kt)
        bfr[kt] = *(const long*)(Lb + ct * 2048 + ktofs[kt]);
      const int colb = chalf * 64 + ct * 16 + l15;
      float csl = 0.f;
#pragma unroll
      for (int rt = 0; rt < 2; ++rt) {
        f32x4 a = {0.f, 0.f, 0.f, 0.f};
#pragma unroll
        for (int kt = 0; kt < 4; ++kt)
          a = __builtin_amdgcn_mfma_f32_16x16x32_fp8_fp8(af[rt][kt], bfr[kt], a, 0, 0, 0);
        // C/D layout (dtype-independent): col = l15, row = q*4 + r
#pragma unroll
        for (int r = 0; r < 4; ++r) {
          float e = __builtin_amdgcn_exp2f(a[r]);
          if (dz && (h * 32 + rt * 16 + q * 4 + r) == colb) e = 0.f;  // mask diag
          rs[rt][r] += e;
          csl += e;
        }
      }
      cstile[ct] = csl;
    }
    // col partial: reduce over q (wave's 32 rows), stash per-(h,chalf) in
    // THIS tile's csbuf buffer; consumed after the NEXT barrier.
#pragma unroll
    for (int m = 16; m <= 32; m <<= 1)
#pragma unroll
      for (int ct = 0; ct < 4; ++ct)
        cstile[ct] += __shfl_xor(cstile[ct], m, 64);
    if (q == 0) {
#pragma unroll
      for (int ct = 0; ct < 4; ++ct)
        csbuf[ti & 1][h * 128 + chalf * 64 + ct * 16 + l15] = cstile[ct];
    }
  }
  __syncthreads();  // csbuf[(ntiles-1)&1] complete
  // colpart store for the last tile
  {
    const int pd = dstart + ntiles - 1;
    if (pd != 0 && pd != 64 && tid < 128) {
      const float* cb = csbuf[(ntiles - 1) & 1];
      colpart[(size_t)(pd - 1) * NROWS + ((I + pd) & 127) * 128 + tid] =
          cb[tid] + cb[128 + tid] + cb[256 + tid] + cb[384 + tid];
    }
  }

  // rows: reduce over the 16 cols (l15) within each wave's 64-col half...
#pragma unroll
  for (int m = 1; m <= 8; m <<= 1)
#pragma unroll
    for (int rt = 0; rt < 2; ++rt)
#pragma unroll
      for (int r = 0; r < 4; ++r)
        rs[rt][r] += __shfl_xor(rs[rt][r], m, 64);
  // ...then combine chalf halves through csbuf[0]; chalf=0 is the unique writer.
  __syncthreads();  // last colpart store done reading csbuf
  if (chalf == 1 && l15 == 0) {
#pragma unroll
    for (int rt = 0; rt < 2; ++rt)
#pragma unroll
      for (int r = 0; r < 4; ++r)
        csbuf[0][h * 32 + rt * 16 + q * 4 + r] = rs[rt][r];
  }
  __syncthreads();
  if (chalf == 0 && l15 == 0) {
#pragma unroll
    for (int rt = 0; rt < 2; ++rt)
#pragma unroll
      for (int r = 0; r < 4; ++r) {
        const int ro = h * 32 + rt * 16 + q * 4 + r;
        rowpart[(size_t)s * NROWS + rI + ro] = rs[rt][r] + csbuf[0][ro];
      }
  }
}

// 64 blocks x 64 threads, 4 rows/thread via float4: sums 8 rowpart +
// 63 colpart slices, adds the analytic diagonal 2^S, logs, wave-reduces.
__global__ void finalize_k(const float* __restrict__ rowpart, const float* __restrict__ colpart,
                           float* __restrict__ accum, int* __restrict__ cnt,
                           float* __restrict__ out) {
  const int tid = threadIdx.x;
  const size_t i4 = (size_t)(blockIdx.x * 64 + tid) * 4;
  const float DIAG = __builtin_exp2f(S_EXP);  // exact e^{1/T}, rows unit-norm
  float4 v = {DIAG, DIAG, DIAG, DIAG};
#pragma unroll
  for (int s2 = 0; s2 < 8; ++s2) {
    float4 t = *(const float4*)&rowpart[(size_t)s2 * NROWS + i4];
    v.x += t.x; v.y += t.y; v.z += t.z; v.w += t.w;
  }
#pragma unroll
  for (int d = 1; d < 64; ++d) {
    float4 t = *(const float4*)&colpart[(size_t)(d - 1) * NROWS + i4];
    v.x += t.x; v.y += t.y; v.z += t.z; v.w += t.w;
  }
  float sm = __logf(v.x) + __logf(v.y) + __logf(v.z) + __logf(v.w);
#pragma unroll
  for (int m = 1; m < 64; m <<= 1) sm += __shfl_xor(sm, m, 64);
  if (tid == 0) {
    atomicAdd(accum, sm);
    __threadfence();
    int prev = atomicAdd(cnt, 1);
    if (prev == (int)gridDim.x - 1) {
      __threadfence();
      float a = __hip_atomic_load(accum, __ATOMIC_RELAXED, __HIP_MEMORY_SCOPE_AGENT);
      out[0] = a / (float)NROWS;
    }
  }
}

extern "C" void kernel_launch(void* const* d_in, const int* in_sizes, int n_in,
                              void* d_out, int out_size, void* d_ws, size_t ws_size,
                              hipStream_t stream) {
  const float* x = (const float*)d_in[0];
  float* out = (float*)d_out;
  // ws layout: xb 2 MB (fp8) | rowpart 8x64KB | colpart 63x64KB | accum,cnt
  unsigned char* xb = (unsigned char*)d_ws;
  float* rowpart = (float*)((char*)d_ws + (size_t)NROWS * DDIM);
  float* colpart = rowpart + (size_t)8 * NROWS;
  float* accum = colpart + (size_t)63 * NROWS;
  int* cnt = (int*)(accum + 1);

  convert_k<<<NROWS * DDIM / (256 * 4), 256, 0, stream>>>(x, xb, accum, cnt);
  gram_tri_k<<<128 * 8, 512, 0, stream>>>(xb, rowpart, colpart);
  finalize_k<<<NROWS / 256, 64, 0, stream>>>(rowpart, colpart, accum, cnt, out);
}